// Round 18
// baseline (138.440 us; speedup 1.0000x reference)
//
#include <hip/hip_runtime.h>
#include <hip/hip_fp16.h>
#include <math.h>

#define NNODES 100000
#define NEDGES 3200000
#define NF 128
#define NH 16
#define SB 192                   // nodes per super-bucket
#define NSB 521                  // ceil(NNODES/SB)
#define NBLK 512                 // blocks for hist/scatter
#define EPB (NEDGES / NBLK)      // 6250 exact
#define CAP2 6912                // max edges/super-bucket
#define XWBLK 391                // ceil(NNODES/256)

__device__ __forceinline__ __half2 u2h(unsigned u) { union { unsigned u; __half2 h; } c; c.u = u; return c.h; }
__device__ __forceinline__ unsigned h2u(__half2 h) { union { unsigned u; __half2 h; } c; c.h = h; return c.u; }
__device__ __forceinline__ __half2 shfl_h2(__half2 v, int m) {
    int x = __shfl_xor(*(int*)&v, m);
    return *(__half2*)&x;
}
__device__ __forceinline__ unsigned f2h(float f) {   // f32 -> f16 bits (u16)
    return h2u(__floats2half2_rn(f, 0.f)) & 0xffffu;
}

// --- fused: super-bucket histogram (blocks 0..511) + x@W1 -> f16 xwh -------
__global__ void k_histxw(const int* __restrict__ col, unsigned* __restrict__ ghist,
                         const float* __restrict__ x, const float* __restrict__ W1,
                         unsigned* __restrict__ xwh) {
    __shared__ float w[NF * NH];     // GEMM role (8 KB)
    __shared__ unsigned h[NSB];      // hist role (2 KB)
    int t = threadIdx.x, b = blockIdx.x;
    if (b < NBLK) {
        for (int i = t; i < NSB; i += 256) h[i] = 0u;
        __syncthreads();
        const int2* c2 = (const int2*)(col + b * EPB);  // 25000B offsets: 8B-aligned
        for (int i = t; i < EPB / 2; i += 256) {
            int2 c = c2[i];
            atomicAdd(&h[(unsigned)c.x / SB], 1u);
            atomicAdd(&h[(unsigned)c.y / SB], 1u);
        }
        __syncthreads();
        for (int i = t; i < NSB; i += 256) ghist[(size_t)b * NSB + i] = h[i];
    } else {
        for (int i = t; i < NF * NH; i += 256) w[i] = W1[i];
        __syncthreads();
        int i = (b - NBLK) * 256 + t;
        if (i >= NNODES) return;
        float acc[NH];
#pragma unroll
        for (int f = 0; f < NH; ++f) acc[f] = 0.f;
        const float4* xr = (const float4*)(x + (long long)i * NF);
#pragma unroll 8
        for (int k4 = 0; k4 < NF / 4; ++k4) {
            float4 v = xr[k4];
            const float* wk = &w[k4 * 4 * NH];
#pragma unroll
            for (int f = 0; f < NH; ++f)
                acc[f] += v.x * wk[f] + v.y * wk[NH + f] + v.z * wk[2 * NH + f] + v.w * wk[3 * NH + f];
        }
        unsigned u[8];
#pragma unroll
        for (int j = 0; j < 8; ++j)
            u[j] = h2u(__floats2half2_rn(acc[2 * j], acc[2 * j + 1]));
        uint4* o = (uint4*)(xwh + (size_t)i * 8);
        o[0] = make_uint4(u[0], u[1], u[2], u[3]);
        o[1] = make_uint4(u[4], u[5], u[6], u[7]);
    }
}

// ---------------- scan 1: per-bucket exclusive scan across blocks ----------
__global__ __launch_bounds__(NBLK) void k_scan1(unsigned* __restrict__ ghist,
                                                unsigned* __restrict__ totals) {
    int k = blockIdx.x, t = threadIdx.x;
    __shared__ unsigned s[NBLK];
    unsigned v = ghist[(size_t)t * NSB + k];
    s[t] = v;
    __syncthreads();
    for (int off = 1; off < NBLK; off <<= 1) {
        unsigned x = (t >= off) ? s[t - off] : 0u;
        __syncthreads();
        s[t] += x;
        __syncthreads();
    }
    ghist[(size_t)t * NSB + k] = s[t] - v;
    if (t == NBLK - 1) totals[k] = s[t];
}

// ------ pass B: write-coalesced scatter; self-computes sbase from totals ---
// payload split: brow u32 (row|ln<<17), bw u16 (f16 weight)
__global__ __launch_bounds__(512) void k_scatB1(
        const int* __restrict__ row, const int* __restrict__ col,
        const float* __restrict__ ew,
        const unsigned* __restrict__ ghist, const unsigned* __restrict__ totals,
        unsigned* __restrict__ brow, unsigned short* __restrict__ bw,
        unsigned* __restrict__ sbase_out) {
    __shared__ unsigned stage_row[EPB];     // 25,000 B
    __shared__ unsigned short stage_w[EPB]; // 12,500 B
    __shared__ unsigned short sbArr[EPB];   // 12,500 B
    __shared__ unsigned lcnt[NSB];
    __shared__ unsigned gdelta[NSB];
    __shared__ unsigned scn[512];
    int t = threadIdx.x, b = blockIdx.x;
    int e0 = b * EPB;
    for (int i = t; i < NSB; i += 512) lcnt[i] = 0u;
    __syncthreads();
    const int2* c2 = (const int2*)(col + e0);
    for (int i = t; i < EPB / 2; i += 512) {
        int2 c = c2[i];
        atomicAdd(&lcnt[(unsigned)c.x / SB], 1u);
        atomicAdd(&lcnt[(unsigned)c.y / SB], 1u);
    }
    __syncthreads();
    // scan A: totals -> local sbase (2 buckets per thread)
    unsigned tv[2];
    unsigned tp = 0;
#pragma unroll
    for (int j = 0; j < 2; ++j) {
        int i = t * 2 + j;
        tv[j] = (i < NSB) ? totals[i] : 0u;
        tp += tv[j];
    }
    scn[t] = tp;
    __syncthreads();
    for (int off = 1; off < 512; off <<= 1) {
        unsigned x = (t >= off) ? scn[t - off] : 0u;
        __syncthreads();
        scn[t] += x;
        __syncthreads();
    }
    unsigned trun = scn[t] - tp;
    unsigned sb_[2];
#pragma unroll
    for (int j = 0; j < 2; ++j) { sb_[j] = trun; trun += tv[j]; }
    __syncthreads();
    // scan B: local hist -> run starts; gdelta
    unsigned v[2];
    unsigned p = 0;
#pragma unroll
    for (int j = 0; j < 2; ++j) {
        int i = t * 2 + j;
        v[j] = (i < NSB) ? lcnt[i] : 0u;
        p += v[j];
    }
    scn[t] = p;
    __syncthreads();
    for (int off = 1; off < 512; off <<= 1) {
        unsigned x = (t >= off) ? scn[t - off] : 0u;
        __syncthreads();
        scn[t] += x;
        __syncthreads();
    }
    unsigned run = scn[t] - p;
    __syncthreads();   // all lcnt reads done before overwrite
    unsigned lst[2];
#pragma unroll
    for (int j = 0; j < 2; ++j) {
        int i = t * 2 + j;
        if (i < NSB) {
            lst[j] = run;
            gdelta[i] = sb_[j] + ghist[(size_t)b * NSB + i] - run;
        }
        run += v[j];
    }
    __syncthreads();
#pragma unroll
    for (int j = 0; j < 2; ++j) {
        int i = t * 2 + j;
        if (i < NSB) lcnt[i] = lst[j];
    }
    if (b == 0) {
#pragma unroll
        for (int j = 0; j < 2; ++j) {
            int i = t * 2 + j;
            if (i < NSB) sbase_out[i] = sb_[j];
        }
        if (t == 0) sbase_out[NSB] = NEDGES;
    }
    __syncthreads();
    // local scatter into LDS stage
    const int2* r2 = (const int2*)(row + e0);
    const float2* w2 = (const float2*)(ew + e0);
    for (int i = t; i < EPB / 2; i += 512) {
        int2 rr = r2[i];
        int2 cc = c2[i];
        float2 ww = w2[i];
        unsigned sb = (unsigned)cc.x / SB;
        unsigned ln = (unsigned)cc.x - sb * SB;
        unsigned pos = atomicAdd(&lcnt[sb], 1u);
        stage_row[pos] = (unsigned)rr.x | (ln << 17);
        stage_w[pos] = (unsigned short)f2h(ww.x);
        sbArr[pos] = (unsigned short)sb;
        sb = (unsigned)cc.y / SB;
        ln = (unsigned)cc.y - sb * SB;
        pos = atomicAdd(&lcnt[sb], 1u);
        stage_row[pos] = (unsigned)rr.y | (ln << 17);
        stage_w[pos] = (unsigned short)f2h(ww.y);
        sbArr[pos] = (unsigned short)sb;
    }
    __syncthreads();
    // coalesced write-out
    for (int i = t; i < EPB; i += 512) {
        unsigned pos = i + gdelta[sbArr[i]];
        brow[pos] = stage_row[i];
        bw[pos] = stage_w[i];
    }
}

// ------- per-bucket: wdeg -> start, dinv, xwn = xwh * half2(dinv) ----------
__global__ __launch_bounds__(1024) void k_degdinv(
        const unsigned* __restrict__ brow, const unsigned short* __restrict__ bw,
        const unsigned* __restrict__ sbase,
        unsigned* __restrict__ start, float* __restrict__ dinv,
        const unsigned* __restrict__ xwh, unsigned* __restrict__ xwn) {
    __shared__ unsigned hist[SB];
    __shared__ float wdeg[SB];
    __shared__ unsigned scn[1024];
    int k = blockIdx.x, t = threadIdx.x;
    unsigned e0 = sbase[k], e1 = sbase[k + 1];
    int ne = (int)(e1 - e0);
    if (t < SB) { hist[t] = 0u; wdeg[t] = 0.f; }
    __syncthreads();
    for (int i = t; i < ne; i += 1024) {
        unsigned p = brow[e0 + i];
        unsigned wu = bw[e0 + i];
        unsigned ln = p >> 17;
        atomicAdd(&hist[ln], 1u);
        atomicAdd(&wdeg[ln], __low2float(u2h(wu)));
    }
    __syncthreads();
    unsigned v = (t < SB) ? hist[t] : 0u;
    scn[t] = v;
    __syncthreads();
    for (int off = 1; off < 1024; off <<= 1) {
        unsigned x = (t >= off) ? scn[t - off] : 0u;
        __syncthreads();
        scn[t] += x;
        __syncthreads();
    }
    unsigned excl = scn[t] - v;
    int g = k * SB + t;
    if (t < SB && g < NNODES) {
        start[g] = e0 + excl;
        float di = rsqrtf(wdeg[t] + 1.0f);   // +1 = self-loop weight
        dinv[g] = di;
        __half2 d2 = __float2half2_rn(di);
        const uint4* xi = (const uint4*)(xwh + (size_t)g * 8);
        uint4 A = xi[0], B = xi[1];
        uint4 o0, o1;
        o0.x = h2u(__hmul2(u2h(A.x), d2));
        o0.y = h2u(__hmul2(u2h(A.y), d2));
        o0.z = h2u(__hmul2(u2h(A.z), d2));
        o0.w = h2u(__hmul2(u2h(A.w), d2));
        o1.x = h2u(__hmul2(u2h(B.x), d2));
        o1.y = h2u(__hmul2(u2h(B.y), d2));
        o1.z = h2u(__hmul2(u2h(B.z), d2));
        o1.w = h2u(__hmul2(u2h(B.w), d2));
        uint4* o = (uint4*)(xwn + (size_t)g * 8);
        o[0] = o0;
        o[1] = o1;
    }
}

// ------- fused: node-sort into LDS + layer-1 compute (NO write-back) -------
// 1024 threads = 16 waves; ~42 KB LDS -> 3 blocks/CU
__global__ __launch_bounds__(1024) void k_sedge1(
        const unsigned* __restrict__ brow, const unsigned short* __restrict__ bw,
        const unsigned* __restrict__ sbase,
        const unsigned* __restrict__ start, const unsigned* __restrict__ xwn,
        const float* __restrict__ dinv, const float* __restrict__ b1,
        const float* __restrict__ W2, float* __restrict__ zn) {
    __shared__ unsigned ed_row[CAP2];        // 27.6 KB
    __shared__ unsigned short ed_w[CAP2];    // 13.8 KB
    __shared__ unsigned lcnt[SB];
    int k = blockIdx.x, t = threadIdx.x;
    unsigned e0 = sbase[k], e1 = sbase[k + 1];
    int ne = (int)(e1 - e0);
    if (t < SB) {
        int g = k * SB + t;
        lcnt[t] = (g < NNODES) ? (start[g] - e0) : (unsigned)ne;
    }
    __syncthreads();
    // scatter into LDS at node-sorted position
    for (int i = t; i < ne; i += 1024) {
        unsigned p = brow[e0 + i];
        unsigned short wu = bw[e0 + i];
        unsigned ln = p >> 17;
        unsigned pos = atomicAdd(&lcnt[ln], 1u);
        ed_row[pos] = p & 0x1FFFFu;
        ed_w[pos] = wu;
    }
    __syncthreads();
    // layer-1 compute straight from LDS (lcnt now holds END offsets)
    int wave = t >> 6, lane = t & 63;
    int fg = lane & 3, e4 = lane >> 2;
#pragma unroll
    for (int j = 0; j < SB / 16; ++j) {       // 12 nodes per wave
        int ln = wave * (SB / 16) + j;
        int g = k * SB + ln;
        if (g >= NNODES) break;
        unsigned o0 = (ln == 0) ? 0u : lcnt[ln - 1];
        unsigned o1 = lcnt[ln];
        __half2 a0 = __float2half2_rn(0.f), a1 = a0;
        for (unsigned e = o0 + e4; e < o1; e += 16) {
            unsigned r = ed_row[e];
            unsigned ww = (unsigned)ed_w[e] * 0x10001u;   // (w,w)
            uint2 q = *(const uint2*)(xwn + (size_t)r * 8 + fg * 2);
            a0 = __hfma2(u2h(q.x), u2h(ww), a0);
            a1 = __hfma2(u2h(q.y), u2h(ww), a1);
        }
#pragma unroll
        for (int m = 4; m < 64; m <<= 1) {
            a0 = __hadd2(a0, shfl_h2(a0, m));
            a1 = __hadd2(a1, shfl_h2(a1, m));
        }
        float ax = __low2float(a0), ay = __high2float(a0);
        float az = __low2float(a1), aw = __high2float(a1);
        // self-loop (xwn already carries dinv[g])
        uint2 qs = *(const uint2*)(xwn + (size_t)g * 8 + fg * 2);
        ax += __low2float(u2h(qs.x)); ay += __high2float(u2h(qs.x));
        az += __low2float(u2h(qs.y)); aw += __high2float(u2h(qs.y));
        float di = dinv[g];
        float4 b4 = ((const float4*)b1)[fg];
        float4 w4 = ((const float4*)W2)[fg];
        float s = fmaxf(di * ax + b4.x, 0.f) * w4.x
                + fmaxf(di * ay + b4.y, 0.f) * w4.y
                + fmaxf(di * az + b4.z, 0.f) * w4.z
                + fmaxf(di * aw + b4.w, 0.f) * w4.w;
        s += __shfl_xor(s, 1);
        s += __shfl_xor(s, 2);
        if (lane == 0) zn[g] = s * di;   // store z * dinv for layer 2
    }
}

// ------ layer 2: per-bucket LDS accumulate (bucket-push) + sigmoid ---------
__global__ __launch_bounds__(512) void k_edge2acc(
        const unsigned* __restrict__ brow, const unsigned short* __restrict__ bw,
        const unsigned* __restrict__ sbase,
        const float* __restrict__ zn, const float* __restrict__ dinv,
        const float* __restrict__ b2, float* __restrict__ out) {
    __shared__ float zacc[SB];
    int k = blockIdx.x, t = threadIdx.x;
    if (t < SB) zacc[t] = 0.f;
    __syncthreads();
    unsigned e0 = sbase[k], e1 = sbase[k + 1];
    for (unsigned e = e0 + t; e < e1; e += 512) {
        unsigned p = brow[e];
        float w = __low2float(u2h((unsigned)bw[e]));
        atomicAdd(&zacc[p >> 17], zn[p & 0x1FFFFu] * w);
    }
    __syncthreads();
    int g = k * SB + t;
    if (t < SB && g < NNODES) {
        float di = dinv[g];
        float v = di * zacc[t] + di * zn[g] + b2[0];
        out[g] = 1.f / (1.f + expf(-v));
    }
}

extern "C" void kernel_launch(void* const* d_in, const int* in_sizes, int n_in,
                              void* d_out, int out_size, void* d_ws, size_t ws_size,
                              hipStream_t stream) {
    const float* x  = (const float*)d_in[0];
    const int* eidx = (const int*)d_in[1];
    const float* ew = (const float*)d_in[2];
    const float* W1 = (const float*)d_in[3];
    const float* b1 = (const float*)d_in[4];
    const float* W2 = (const float*)d_in[5];
    const float* b2 = (const float*)d_in[6];
    float* out = (float*)d_out;

    const int* row = eidx;           // edge_index[0]
    const int* col = eidx + NEDGES;  // edge_index[1]

    // workspace layout (4-byte words), total ~27.9 MB
    unsigned* ws = (unsigned*)d_ws;
    unsigned*       brow   = ws;                          // 3,200,000
    unsigned short* bw     = (unsigned short*)(ws + 3200000);  // 1,600,000 words
    unsigned*       xwh    = ws + 4800000;                //   800,000 (f16 x@W1)
    unsigned*       xwn    = ws + 5600000;                //   800,000 (f16*dinv)
    float*          dinv   = (float*)(ws + 6400000);      //   100,000
    float*          zn     = (float*)(ws + 6500000);      //   100,000
    unsigned*       start  = ws + 6600000;                //   100,000
    unsigned*       sbase  = ws + 6700000;                //       522
    unsigned*       totals = ws + 6700522;                //       521
    unsigned*       ghist  = ws + 6701043;                //   266,752 (NBLK*NSB)

    k_histxw <<<NBLK + XWBLK, 256, 0, stream>>>(col, ghist, x, W1, xwh);
    k_scan1  <<<NSB, NBLK, 0, stream>>>(ghist, totals);
    k_scatB1 <<<NBLK, 512, 0, stream>>>(row, col, ew, ghist, totals, brow, bw, sbase);
    k_degdinv<<<NSB, 1024, 0, stream>>>(brow, bw, sbase, start, dinv, xwh, xwn);
    k_sedge1 <<<NSB, 1024, 0, stream>>>(brow, bw, sbase, start, xwn, dinv, b1, W2, zn);
    k_edge2acc<<<NSB, 512, 0, stream>>>(brow, bw, sbase, zn, dinv, b2, out);
}

// Round 19
// 134.753 us; speedup vs baseline: 1.0274x; 1.0274x over previous
//
#include <hip/hip_runtime.h>
#include <hip/hip_fp16.h>
#include <math.h>

#define NNODES 100000
#define NEDGES 3200000
#define NF 128
#define NH 16
#define SB 192                   // nodes per super-bucket
#define NSB 521                  // ceil(NNODES/SB)
#define NBLK 512                 // blocks for hist/scatter
#define EPB (NEDGES / NBLK)      // 6250 exact
#define CAP2 6912                // max edges/super-bucket
#define XWBLK 391                // ceil(NNODES/256)

__device__ __forceinline__ __half2 u2h(unsigned u) { union { unsigned u; __half2 h; } c; c.u = u; return c.h; }
__device__ __forceinline__ unsigned h2u(__half2 h) { union { unsigned u; __half2 h; } c; c.h = h; return c.u; }
__device__ __forceinline__ __half2 shfl_h2(__half2 v, int m) {
    int x = __shfl_xor(*(int*)&v, m);
    return *(__half2*)&x;
}

// ------ fused: super-bucket histogram (blocks 0..511) + x@W1 fp32 (rest) ---
__global__ void k_histxw(const int* __restrict__ col, unsigned* __restrict__ ghist,
                         const float* __restrict__ x, const float* __restrict__ W1,
                         float* __restrict__ xw) {
    __shared__ float w[NF * NH];     // GEMM role (8 KB)
    __shared__ unsigned h[NSB];      // hist role (2 KB)
    int t = threadIdx.x, b = blockIdx.x;
    if (b < NBLK) {
        for (int i = t; i < NSB; i += 256) h[i] = 0u;
        __syncthreads();
        const int2* c2 = (const int2*)(col + b * EPB);  // 25000B offsets: 8B-aligned
        for (int i = t; i < EPB / 2; i += 256) {
            int2 c = c2[i];
            atomicAdd(&h[(unsigned)c.x / SB], 1u);
            atomicAdd(&h[(unsigned)c.y / SB], 1u);
        }
        __syncthreads();
        for (int i = t; i < NSB; i += 256) ghist[(size_t)b * NSB + i] = h[i];
    } else {
        for (int i = t; i < NF * NH; i += 256) w[i] = W1[i];
        __syncthreads();
        int i = (b - NBLK) * 256 + t;
        if (i >= NNODES) return;
        float acc[NH];
#pragma unroll
        for (int f = 0; f < NH; ++f) acc[f] = 0.f;
        const float4* xr = (const float4*)(x + (long long)i * NF);
#pragma unroll 8
        for (int k4 = 0; k4 < NF / 4; ++k4) {
            float4 v = xr[k4];
            const float* wk = &w[k4 * 4 * NH];
#pragma unroll
            for (int f = 0; f < NH; ++f)
                acc[f] += v.x * wk[f] + v.y * wk[NH + f] + v.z * wk[2 * NH + f] + v.w * wk[3 * NH + f];
        }
        float4* o = (float4*)(xw + (size_t)i * NH);
#pragma unroll
        for (int q = 0; q < 4; ++q)
            o[q] = make_float4(acc[4 * q], acc[4 * q + 1], acc[4 * q + 2], acc[4 * q + 3]);
    }
}

// ---------------- scan 1: per-bucket exclusive scan across blocks ----------
__global__ __launch_bounds__(NBLK) void k_scan1(unsigned* __restrict__ ghist,
                                                unsigned* __restrict__ totals) {
    int k = blockIdx.x, t = threadIdx.x;
    __shared__ unsigned s[NBLK];
    unsigned v = ghist[(size_t)t * NSB + k];
    s[t] = v;
    __syncthreads();
    for (int off = 1; off < NBLK; off <<= 1) {
        unsigned x = (t >= off) ? s[t - off] : 0u;
        __syncthreads();
        s[t] += x;
        __syncthreads();
    }
    ghist[(size_t)t * NSB + k] = s[t] - v;
    if (t == NBLK - 1) totals[k] = s[t];
}

// ------ pass B: write-coalesced scatter; self-computes sbase from totals ---
__global__ __launch_bounds__(512) void k_scatB1(
        const int* __restrict__ row, const int* __restrict__ col,
        const float* __restrict__ ew,
        const unsigned* __restrict__ ghist, const unsigned* __restrict__ totals,
        uint2* __restrict__ spack, unsigned* __restrict__ sbase_out) {
    __shared__ uint2 stage[EPB];            // 50,000 B
    __shared__ unsigned short sbArr[EPB];   // 12,500 B
    __shared__ unsigned lcnt[NSB];
    __shared__ unsigned gdelta[NSB];
    __shared__ unsigned scn[512];
    int t = threadIdx.x, b = blockIdx.x;
    int e0 = b * EPB;
    for (int i = t; i < NSB; i += 512) lcnt[i] = 0u;
    __syncthreads();
    const int2* c2 = (const int2*)(col + e0);
    for (int i = t; i < EPB / 2; i += 512) {
        int2 c = c2[i];
        atomicAdd(&lcnt[(unsigned)c.x / SB], 1u);
        atomicAdd(&lcnt[(unsigned)c.y / SB], 1u);
    }
    __syncthreads();
    // scan A: totals -> local sbase (2 buckets per thread)
    unsigned tv[2];
    unsigned tp = 0;
#pragma unroll
    for (int j = 0; j < 2; ++j) {
        int i = t * 2 + j;
        tv[j] = (i < NSB) ? totals[i] : 0u;
        tp += tv[j];
    }
    scn[t] = tp;
    __syncthreads();
    for (int off = 1; off < 512; off <<= 1) {
        unsigned x = (t >= off) ? scn[t - off] : 0u;
        __syncthreads();
        scn[t] += x;
        __syncthreads();
    }
    unsigned trun = scn[t] - tp;
    unsigned sb_[2];
#pragma unroll
    for (int j = 0; j < 2; ++j) { sb_[j] = trun; trun += tv[j]; }
    __syncthreads();
    // scan B: local hist -> run starts; gdelta
    unsigned v[2];
    unsigned p = 0;
#pragma unroll
    for (int j = 0; j < 2; ++j) {
        int i = t * 2 + j;
        v[j] = (i < NSB) ? lcnt[i] : 0u;
        p += v[j];
    }
    scn[t] = p;
    __syncthreads();
    for (int off = 1; off < 512; off <<= 1) {
        unsigned x = (t >= off) ? scn[t - off] : 0u;
        __syncthreads();
        scn[t] += x;
        __syncthreads();
    }
    unsigned run = scn[t] - p;
    __syncthreads();   // all lcnt reads done before overwrite
    unsigned lst[2];
#pragma unroll
    for (int j = 0; j < 2; ++j) {
        int i = t * 2 + j;
        if (i < NSB) {
            lst[j] = run;
            gdelta[i] = sb_[j] + ghist[(size_t)b * NSB + i] - run;
        }
        run += v[j];
    }
    __syncthreads();
#pragma unroll
    for (int j = 0; j < 2; ++j) {
        int i = t * 2 + j;
        if (i < NSB) lcnt[i] = lst[j];
    }
    if (b == 0) {
#pragma unroll
        for (int j = 0; j < 2; ++j) {
            int i = t * 2 + j;
            if (i < NSB) sbase_out[i] = sb_[j];
        }
        if (t == 0) sbase_out[NSB] = NEDGES;
    }
    __syncthreads();
    // local scatter into LDS stage
    const int2* r2 = (const int2*)(row + e0);
    const float2* w2 = (const float2*)(ew + e0);
    for (int i = t; i < EPB / 2; i += 512) {
        int2 rr = r2[i];
        int2 cc = c2[i];
        float2 ww = w2[i];
        unsigned sb = (unsigned)cc.x / SB;
        unsigned ln = (unsigned)cc.x - sb * SB;
        unsigned pos = atomicAdd(&lcnt[sb], 1u);
        stage[pos] = make_uint2((unsigned)rr.x | (ln << 17), __float_as_uint(ww.x));
        sbArr[pos] = (unsigned short)sb;
        sb = (unsigned)cc.y / SB;
        ln = (unsigned)cc.y - sb * SB;
        pos = atomicAdd(&lcnt[sb], 1u);
        stage[pos] = make_uint2((unsigned)rr.y | (ln << 17), __float_as_uint(ww.y));
        sbArr[pos] = (unsigned short)sb;
    }
    __syncthreads();
    // coalesced write-out
    for (int i = t; i < EPB; i += 512)
        spack[i + gdelta[sbArr[i]]] = stage[i];
}

// ------- per-bucket: wdeg -> start, dinv, dinv-scaled f16 xwn table --------
__global__ __launch_bounds__(512) void k_degdinv(
        const uint2* __restrict__ spack, const unsigned* __restrict__ sbase,
        unsigned* __restrict__ start, float* __restrict__ dinv,
        const float* __restrict__ xw, unsigned* __restrict__ xwn) {
    __shared__ unsigned hist[SB];
    __shared__ float wdeg[SB];
    __shared__ unsigned scn[512];
    int k = blockIdx.x, t = threadIdx.x;
    unsigned e0 = sbase[k], e1 = sbase[k + 1];
    int ne = (int)(e1 - e0);
    if (t < SB) { hist[t] = 0u; wdeg[t] = 0.f; }
    __syncthreads();
    for (int i = t; i < ne; i += 512) {
        uint2 p = spack[e0 + i];
        unsigned ln = p.x >> 17;
        atomicAdd(&hist[ln], 1u);
        atomicAdd(&wdeg[ln], __uint_as_float(p.y));
    }
    __syncthreads();
    unsigned v = (t < SB) ? hist[t] : 0u;
    scn[t] = v;
    __syncthreads();
    for (int off = 1; off < 512; off <<= 1) {
        unsigned x = (t >= off) ? scn[t - off] : 0u;
        __syncthreads();
        scn[t] += x;
        __syncthreads();
    }
    unsigned excl = scn[t] - v;
    int g = k * SB + t;
    if (t < SB && g < NNODES) {
        start[g] = e0 + excl;
        float di = rsqrtf(wdeg[t] + 1.0f);   // +1 = self-loop weight
        dinv[g] = di;
        const float4* xr = (const float4*)(xw + (size_t)g * NH);
        float4 A = xr[0], B = xr[1], C = xr[2], D = xr[3];
        uint4 o0, o1;
        o0.x = h2u(__floats2half2_rn(A.x * di, A.y * di));
        o0.y = h2u(__floats2half2_rn(A.z * di, A.w * di));
        o0.z = h2u(__floats2half2_rn(B.x * di, B.y * di));
        o0.w = h2u(__floats2half2_rn(B.z * di, B.w * di));
        o1.x = h2u(__floats2half2_rn(C.x * di, C.y * di));
        o1.y = h2u(__floats2half2_rn(C.z * di, C.w * di));
        o1.z = h2u(__floats2half2_rn(D.x * di, D.y * di));
        o1.w = h2u(__floats2half2_rn(D.z * di, D.w * di));
        uint4* o = (uint4*)(xwn + (size_t)g * 8);
        o[0] = o0;
        o[1] = o1;
    }
}

// ------- fused: node-sort into LDS + layer-1 compute (NO write-back) -------
// 1024 threads = 16 waves; 2-slot unroll -> 32 edges in flight per node
__global__ __launch_bounds__(1024) void k_sedge1(
        const uint2* __restrict__ spack, const unsigned* __restrict__ sbase,
        const unsigned* __restrict__ start, const unsigned* __restrict__ xwn,
        const float* __restrict__ dinv, const float* __restrict__ b1,
        const float* __restrict__ W2, float* __restrict__ zn) {
    __shared__ uint2 ed[CAP2];        // 55.3 KB node-sorted (row, half2 w)
    __shared__ unsigned lcnt[SB];
    int k = blockIdx.x, t = threadIdx.x;
    unsigned e0 = sbase[k], e1 = sbase[k + 1];
    int ne = (int)(e1 - e0);
    if (t < SB) {
        int g = k * SB + t;
        lcnt[t] = (g < NNODES) ? (start[g] - e0) : (unsigned)ne;
    }
    __syncthreads();
    // scatter into LDS at node-sorted position; convert w -> half2(w,w)
    for (int i = t; i < ne; i += 1024) {
        uint2 p = spack[e0 + i];
        unsigned ln = p.x >> 17;
        unsigned pos = atomicAdd(&lcnt[ln], 1u);
        __half2 hw = __float2half2_rn(__uint_as_float(p.y));
        ed[pos] = make_uint2(p.x & 0x1FFFFu, h2u(hw));
    }
    __syncthreads();
    // layer-1 compute straight from LDS (lcnt now holds END offsets)
    int wave = t >> 6, lane = t & 63;
    int fg = lane & 3, e4 = lane >> 2;
#pragma unroll
    for (int j = 0; j < SB / 16; ++j) {       // 12 nodes per wave
        int ln = wave * (SB / 16) + j;
        int g = k * SB + ln;
        if (g >= NNODES) break;
        unsigned o0 = (ln == 0) ? 0u : lcnt[ln - 1];
        unsigned o1 = lcnt[ln];
        __half2 a0 = __float2half2_rn(0.f), a1 = a0;
        for (unsigned e = o0 + e4; e < o1; e += 32) {
            unsigned eb = e + 16;
            bool vb = eb < o1;
            uint2 d0 = ed[e];
            uint2 d1 = ed[vb ? eb : e];       // always-valid LDS index; same row when dead
            unsigned w1 = vb ? d1.y : 0u;     // dead slot contributes 0
            uint2 q0 = *(const uint2*)(xwn + (size_t)d0.x * 8 + fg * 2);
            uint2 q1 = *(const uint2*)(xwn + (size_t)d1.x * 8 + fg * 2);
            a0 = __hfma2(u2h(q0.x), u2h(d0.y), a0);
            a1 = __hfma2(u2h(q0.y), u2h(d0.y), a1);
            a0 = __hfma2(u2h(q1.x), u2h(w1), a0);
            a1 = __hfma2(u2h(q1.y), u2h(w1), a1);
        }
#pragma unroll
        for (int m = 4; m < 64; m <<= 1) {
            a0 = __hadd2(a0, shfl_h2(a0, m));
            a1 = __hadd2(a1, shfl_h2(a1, m));
        }
        float ax = __low2float(a0), ay = __high2float(a0);
        float az = __low2float(a1), aw = __high2float(a1);
        // self-loop (xwn already carries dinv[g])
        uint2 qs = *(const uint2*)(xwn + (size_t)g * 8 + fg * 2);
        ax += __low2float(u2h(qs.x)); ay += __high2float(u2h(qs.x));
        az += __low2float(u2h(qs.y)); aw += __high2float(u2h(qs.y));
        float di = dinv[g];
        float4 b4 = ((const float4*)b1)[fg];
        float4 w4 = ((const float4*)W2)[fg];
        float s = fmaxf(di * ax + b4.x, 0.f) * w4.x
                + fmaxf(di * ay + b4.y, 0.f) * w4.y
                + fmaxf(di * az + b4.z, 0.f) * w4.z
                + fmaxf(di * aw + b4.w, 0.f) * w4.w;
        s += __shfl_xor(s, 1);
        s += __shfl_xor(s, 2);
        if (lane == 0) zn[g] = s * di;   // store z * dinv for layer 2
    }
}

// ------ layer 2: per-bucket LDS accumulate (bucket-push) + sigmoid ---------
__global__ __launch_bounds__(512) void k_edge2acc(
        const uint2* __restrict__ spack, const unsigned* __restrict__ sbase,
        const float* __restrict__ zn, const float* __restrict__ dinv,
        const float* __restrict__ b2, float* __restrict__ out) {
    __shared__ float zacc[SB];
    int k = blockIdx.x, t = threadIdx.x;
    if (t < SB) zacc[t] = 0.f;
    __syncthreads();
    unsigned e0 = sbase[k], e1 = sbase[k + 1];
    for (unsigned e = e0 + t; e < e1; e += 512) {
        uint2 p = spack[e];
        atomicAdd(&zacc[p.x >> 17], zn[p.x & 0x1FFFFu] * __uint_as_float(p.y));
    }
    __syncthreads();
    int g = k * SB + t;
    if (t < SB && g < NNODES) {
        float di = dinv[g];
        float v = di * zacc[t] + di * zn[g] + b2[0];
        out[g] = 1.f / (1.f + expf(-v));
    }
}

extern "C" void kernel_launch(void* const* d_in, const int* in_sizes, int n_in,
                              void* d_out, int out_size, void* d_ws, size_t ws_size,
                              hipStream_t stream) {
    const float* x  = (const float*)d_in[0];
    const int* eidx = (const int*)d_in[1];
    const float* ew = (const float*)d_in[2];
    const float* W1 = (const float*)d_in[3];
    const float* b1 = (const float*)d_in[4];
    const float* W2 = (const float*)d_in[5];
    const float* b2 = (const float*)d_in[6];
    float* out = (float*)d_out;

    const int* row = eidx;           // edge_index[0]
    const int* col = eidx + NEDGES;  // edge_index[1]

    // workspace layout (4-byte words), total ~37.5 MB
    unsigned* ws = (unsigned*)d_ws;
    uint2*    spack  = (uint2*)ws;                       // 6,400,000 words
    float*    xw     = (float*)(ws + 6400000);           // 1,600,000 (fp32 x@W1)
    unsigned* xwn    = ws + 8000000;                     //   800,000 (f16*dinv table)
    float*    dinv   = (float*)(ws + 8800000);           //   100,000
    float*    zn     = (float*)(ws + 8900000);           //   100,000
    unsigned* start  = ws + 9000000;                     //   100,000
    unsigned* sbase  = ws + 9100000;                     //       522
    unsigned* totals = ws + 9100522;                     //       521
    unsigned* ghist  = ws + 9101043;                     //   266,752 (NBLK*NSB)

    k_histxw <<<NBLK + XWBLK, 256, 0, stream>>>(col, ghist, x, W1, xw);
    k_scan1  <<<NSB, NBLK, 0, stream>>>(ghist, totals);
    k_scatB1 <<<NBLK, 512, 0, stream>>>(row, col, ew, ghist, totals, spack, sbase);
    k_degdinv<<<NSB, 512, 0, stream>>>(spack, sbase, start, dinv, xw, xwn);
    k_sedge1 <<<NSB, 1024, 0, stream>>>(spack, sbase, start, xwn, dinv, b1, W2, zn);
    k_edge2acc<<<NSB, 512, 0, stream>>>(spack, sbase, zn, dinv, b2, out);
}